// Round 18
// baseline (145.420 us; speedup 1.0000x reference)
//
#include <hip/hip_runtime.h>

// GraphConvolution: out = relu(D^-1/2 (2I - adj) D^-1/2 (input@weight) + b)
// N=8192, F_in=512, F_out=256. fp16 MFMA internally (needs 2^-12 rounding).
//
// R18 = R17 with the stageB bug fixed: global_load_lds needs a PER-LANE
// global source (lane l's fragment = byte l*16 of each 1024B half); R17
// passed a wave-uniform pointer -> broadcast garbage. All else unchanged:
// k3 at BM=32, 4 blocks/CU, B via per-wave LDS (no async data VGPRs),
// counted vmcnt (2 ops in flight across every barrier).

typedef _Float16 h4 __attribute__((ext_vector_type(4)));
typedef _Float16 h8 __attribute__((ext_vector_type(8)));
typedef float f4 __attribute__((ext_vector_type(4)));

__device__ __forceinline__ void gload_lds16(const void* g, void* l) {
    __builtin_amdgcn_global_load_lds(
        (const __attribute__((address_space(1))) void*)g,
        (__attribute__((address_space(3))) void*)l, 16, 0, 0);
}
__device__ __forceinline__ void gloadA1(const float* p, f4& x) {
    asm volatile("global_load_dwordx4 %0, %1, off"
                 : "=&v"(x) : "v"(p) : "memory");
}

// ---------------------------------------------------------------------------
// k0: weight [512][256] f32 -> W^T fp16, XOR-swizzled per 128B k-chunk:
// byte ^= ((j&7)<<4)  (consumed by the fused kernel's gload_lds path).
__global__ __launch_bounds__(256) void k0_wt(const float* __restrict__ weight,
                                             char* __restrict__ wt) {
    const int idx = blockIdx.x * 256 + threadIdx.x;   // 131072 total
    const int k = idx >> 8, j = idx & 255;
    const _Float16 h = (_Float16)weight[idx];
    const int off = j * 1024 + ((k >> 6) << 7) + (((k & 63) << 1) ^ ((j & 7) << 4));
    *(_Float16*)(wt + off) = h;
}

// ---------------------------------------------------------------------------
// fragT layout of S^T (4 MB): chunk = (j>>4)*128 + (k>>6), 2048B each;
// off = chunk*2048 + ((k>>5)&1)*1024 + (((k>>3)&3)*16+(j&15))*16 + (k&7)*2.
// Lane l of a wave reading chunk base + l*16 gets exactly its MFMA B-fragment.
//
// k12: fused. bid<256: support = input@weight -> fragT (raw, no dinv).
// bid>=256: rowsum of adj row (bid-256) -> dinv.
__global__ __launch_bounds__(512) void k12_fused(const float* __restrict__ input,
                                                 const float* __restrict__ adj,
                                                 const char* __restrict__ wt,
                                                 float* __restrict__ dinv,
                                                 char* __restrict__ sT) {
    __shared__ char smem[4096 + 32768];
    const int bid = (int)blockIdx.x, t = (int)threadIdx.x;

    if (bid >= 256) {   // ---- k1: rowsum, full occupancy
        const int r = bid - 256;
        const float4* rp = (const float4*)(adj + (size_t)r * 8192);
        float s = 0.f;
#pragma unroll
        for (int i = 0; i < 4; ++i) {
            float4 v = rp[t + i * 512];
            s += (v.x + v.y) + (v.z + v.w);
        }
#pragma unroll
        for (int off = 32; off > 0; off >>= 1) s += __shfl_down(s, off, 64);
        float* part = (float*)smem;
        if ((t & 63) == 0) part[t >> 6] = s;
        __syncthreads();
        if (t == 0) {
            float deg = ((part[0] + part[1]) + (part[2] + part[3])) +
                        ((part[4] + part[5]) + (part[6] + part[7]));
            dinv[r] = 1.0f / sqrtf(2.0f + deg);
        }
        return;
    }

    // ---- k2: support GEMM ----
    const int w = t >> 6, l = t & 63;
    const int r0 = bid * 32;
    const int arow = t >> 4, ak4 = t & 15;
    const int bj = l >> 3, bb = (l & 7) * 16;

    f4 acc[2][2] = {};

    for (int kt = 0; kt < 8; ++kt) {
        const int k0 = kt * 64;
        __syncthreads();
        {
            float4 v = *(const float4*)(input + (size_t)(r0 + arow) * 512 + k0 + ak4 * 4);
            h4 h;
            h[0] = (_Float16)v.x; h[1] = (_Float16)v.y;
            h[2] = (_Float16)v.z; h[3] = (_Float16)v.w;
            *(h4*)(smem + arow * 128 + ((ak4 * 8) ^ ((arow & 7) << 4))) = h;
        }
#pragma unroll
        for (int q = 0; q < 4; ++q) {
            const int c = q * 8 + w;
            gload_lds16(wt + (size_t)(c * 8 + bj) * 1024 + kt * 128 + bb,
                        smem + 4096 + c * 1024);
        }
        __syncthreads();
#pragma unroll
        for (int kk = 0; kk < 2; ++kk) {
            const int ko = kk * 64 + ((l >> 4) << 4);
            h8 a[2], b[2];
#pragma unroll
            for (int m = 0; m < 2; ++m) {
                const int r = m * 16 + (l & 15);
                a[m] = *(const h8*)(smem + r * 128 + (ko ^ ((r & 7) << 4)));
            }
#pragma unroll
            for (int n = 0; n < 2; ++n) {
                const int j = w * 32 + n * 16 + (l & 15);
                b[n] = *(const h8*)(smem + 4096 + j * 128 + (ko ^ ((j & 7) << 4)));
            }
#pragma unroll
            for (int m = 0; m < 2; ++m)
#pragma unroll
                for (int n = 0; n < 2; ++n)
                    acc[m][n] = __builtin_amdgcn_mfma_f32_16x16x32_f16(a[m], b[n], acc[m][n], 0, 0, 0);
        }
    }
#pragma unroll
    for (int m = 0; m < 2; ++m)
#pragma unroll
        for (int n = 0; n < 2; ++n) {
            const int j = w * 32 + n * 16 + (l & 15);
            const int k0r = r0 + m * 16 + ((l >> 4) << 2);
            h4 h;
#pragma unroll
            for (int r = 0; r < 4; ++r)
                h[r] = (_Float16)acc[m][n][r];
            const int off = (((j >> 4) * 128 + (k0r >> 6)) << 11) +
                            (((k0r >> 5) & 1) << 10) +
                            ((((k0r >> 3) & 3) << 4) + (j & 15)) * 16 +
                            ((k0r & 7) << 1);
            *(h4*)(sT + off) = h;
        }
}

// ---------------------------------------------------------------------------
// k3: partial[i][j] = sum_{k slice} (2I-adj)[i][k]*dinv[k] * S^T[j][k].
// BM=32, BN=256, BK=64; 8 waves x (32Mx32N); grid (256, nsplit).
// A: f32 asm load -> fp16(dinv-scaled) -> LDS dbuf (2x4KB).
// B: global_load_lds (PER-LANE source +l*16) into per-wave LDS (4KB/wave).
// dinv: per-thread asm f4 load (ping-ponged). Steady vmcnt: issue
// [stageB(kt)x4, d(kt+2), a(kt+2)]; vmcnt(2) releases B(kt)+d/a(kt+1);
// [d,a](kt+2) stay in flight across the barrier (T4).
__global__ __launch_bounds__(512, 8) void k3_spmm(const float* __restrict__ adj,
                                                  const char* __restrict__ sT,
                                                  const float* __restrict__ dinvg,
                                                  _Float16* __restrict__ parth,
                                                  float* __restrict__ out,
                                                  int steps) {
    __shared__ __align__(16) char smemA[2][4096];   // A tiles [32 rows][128 B]
    __shared__ __align__(16) char smemB[8][4096];   // per-wave B (2 chunks)
    const int t = threadIdx.x;
    const int w = t >> 6, l = t & 63;
    const int i0 = (int)blockIdx.x * 32;
    const int ks0 = (int)blockIdx.y * steps * 64;
    const int dkt = (i0 - ks0) >> 6;   // step holding the diagonal (or out of range)

    const int arow = t >> 4;           // 0..31 (16 threads per row)
    const int ak4 = t & 15;            // f4 index along k
    const int arow_g = i0 + arow;
    const float* aptr = adj + (size_t)arow_g * 8192 + ks0 + ak4 * 4;
    const float* dptr = dinvg + ks0 + ak4 * 4;
    const int a_off = arow * 128 + ((ak4 * 8) ^ ((arow & 7) << 4));

    // B source: wave w owns j-blocks 2w, 2w+1; lane l's fragment at +l*16.
    const char* bsrc = sT + ((size_t)(w * 2) * 128 + (ks0 >> 6)) * 2048 + l * 16;
    char* bl = smemB[w];

    f4 acc[2][2] = {};                 // 16 AGPR
    f4 ax0, ax1, d0, d1;               // async asm regs (16 VGPR)

    auto stageB = [&](int kt) {        // 4 gload_lds, per-lane sources
        const char* s0 = bsrc + (size_t)kt * 2048;
        gload_lds16(s0, bl);
        gload_lds16(s0 + 1024, bl + 1024);
        gload_lds16(s0 + 262144, bl + 2048);            // n=1 chunk (+128*2048)
        gload_lds16(s0 + 262144 + 1024, bl + 3072);
    };
    auto writeA = [&](char* buf, int kt, const f4 x, const f4 d) {
        const int kg = ks0 + kt * 64 + ak4 * 4;
        h4 h;
        if (kt == dkt) {
            h[0] = (_Float16)(d[0] * ((arow_g == kg    ) ? 2.0f - x[0] : -x[0]));
            h[1] = (_Float16)(d[1] * ((arow_g == kg + 1) ? 2.0f - x[1] : -x[1]));
            h[2] = (_Float16)(d[2] * ((arow_g == kg + 2) ? 2.0f - x[2] : -x[2]));
            h[3] = (_Float16)(d[3] * ((arow_g == kg + 3) ? 2.0f - x[3] : -x[3]));
        } else {
            h[0] = (_Float16)(-d[0] * x[0]);
            h[1] = (_Float16)(-d[1] * x[1]);
            h[2] = (_Float16)(-d[2] * x[2]);
            h[3] = (_Float16)(-d[3] * x[3]);
        }
        *(h4*)(buf + a_off) = h;
    };
    auto compute = [&](const char* A) {
        __builtin_amdgcn_s_setprio(1);                       // T5
#pragma unroll
        for (int kk = 0; kk < 2; ++kk) {
            const int ko = kk * 64 + ((l >> 4) << 4);
            h8 a[2], b[2];
#pragma unroll
            for (int m = 0; m < 2; ++m) {
                const int r = m * 16 + (l & 15);
                a[m] = *(const h8*)(A + r * 128 + (ko ^ ((r & 7) << 4)));
            }
#pragma unroll
            for (int n = 0; n < 2; ++n)
                b[n] = *(const h8*)(bl + n * 2048 + kk * 1024 + l * 16);
#pragma unroll
            for (int m = 0; m < 2; ++m)
#pragma unroll
                for (int n = 0; n < 2; ++n)
                    acc[m][n] = __builtin_amdgcn_mfma_f32_16x16x32_f16(a[m], b[n], acc[m][n], 0, 0, 0);
        }
        __builtin_amdgcn_s_setprio(0);                       // T5
    };

#define SBAR0() __builtin_amdgcn_sched_barrier(0)
#define WAIT_VM0(X0, X1)                                                      \
    asm volatile("s_waitcnt vmcnt(0)" : "+v"(X0), "+v"(X1) :: "memory");      \
    SBAR0();
#define WAIT_STEP(X, D)                                                       \
    asm volatile("s_waitcnt vmcnt(2)" : "+v"(X), "+v"(D) :: "memory");        \
    SBAR0();
#define BARRIER()                                                             \
    asm volatile("s_waitcnt lgkmcnt(0)\n\ts_barrier" ::: "memory");           \
    SBAR0();

    // prologue: load d(0),a(0); drain; writeA(0); load d(1),a(1); barrier.
    gloadA1(dptr, d0);
    gloadA1(aptr, ax0);
    WAIT_VM0(ax0, d0)
    writeA(smemA[0], 0, ax0, d0);
    gloadA1(dptr + 64, d1);
    gloadA1(aptr + 64, ax1);
    BARRIER()                          // A(0) visible; [d(1),a(1)] in flight

    // BODY(kt): stageB(kt); issue d/a(kt+2); vmcnt(2) -> B(kt) in LDS +
    // d/a(kt+1) in regs; writeA(kt+1); compute(kt); barrier.
#define BODY(kt, AXC, DC, AXN, DN, BUFC, BUFN)                                \
    {                                                                         \
        stageB(kt);                                                           \
        gloadA1(dptr + (size_t)((kt) + 2) * 64, DC);                          \
        gloadA1(aptr + (size_t)((kt) + 2) * 64, AXC);                         \
        WAIT_STEP(AXN, DN)                                                    \
        writeA(BUFN, (kt) + 1, AXN, DN);                                      \
        compute(BUFC);                                                        \
        BARRIER()                                                             \
    }

    for (int kt2 = 0; kt2 + 2 <= steps - 2; kt2 += 2) {
        BODY(kt2,     ax0, d0, ax1, d1, smemA[0], smemA[1])
        BODY(kt2 + 1, ax1, d1, ax0, d0, smemA[1], smemA[0])
    }
    {   // tail kt = steps-2: no new d/a issue
        stageB(steps - 2);
        WAIT_VM0(ax1, d1)
        writeA(smemA[1], steps - 1, ax1, d1);
        compute(smemA[0]);
        BARRIER()
    }
    {   // tail kt = steps-1
        stageB(steps - 1);
        asm volatile("s_waitcnt vmcnt(0)" ::: "memory");
        SBAR0();
        compute(smemA[1]);
    }
#undef BODY
#undef WAIT_VM0
#undef WAIT_STEP
#undef BARRIER
#undef SBAR0

    // epilogue: last split -> f32 out; others -> fp16 partial slot.
    if (blockIdx.y == gridDim.y - 1) {
#pragma unroll
        for (int m = 0; m < 2; ++m)
#pragma unroll
            for (int n = 0; n < 2; ++n) {
                const int j = w * 32 + n * 16 + (l & 15);
                const int ib = i0 + m * 16 + ((l >> 4) << 2);
#pragma unroll
                for (int r = 0; r < 4; ++r)
                    out[(size_t)(ib + r) * 256 + j] = acc[m][n][r];
            }
    } else {
        _Float16* pslot = parth + (size_t)blockIdx.y * (8192 * 256);
#pragma unroll
        for (int m = 0; m < 2; ++m)
#pragma unroll
            for (int n = 0; n < 2; ++n) {
                const int j = w * 32 + n * 16 + (l & 15);
                const int ib = i0 + m * 16 + ((l >> 4) << 2);
#pragma unroll
                for (int r = 0; r < 4; ++r)
                    pslot[(size_t)(ib + r) * 256 + j] = (_Float16)acc[m][n][r];
            }
    }
}

// ---------------------------------------------------------------------------
// k4: out = relu(dinv[i]*(out + sum of fp16 partials) + b[j]).
__global__ __launch_bounds__(256) void k4_fin(const _Float16* __restrict__ parth,
                                              float* __restrict__ out,
                                              const float* __restrict__ dinv,
                                              const float* __restrict__ bias,
                                              int nsplit) {
    const int idx = blockIdx.x * 256 + threadIdx.x;   // 524288 float4 groups
    float4 s = ((const float4*)out)[idx];
    for (int sp = 0; sp < nsplit - 1; ++sp) {
        const h4 p = *(const h4*)(parth + (size_t)sp * (8192 * 256) + (size_t)idx * 4);
        s.x += (float)p[0]; s.y += (float)p[1];
        s.z += (float)p[2]; s.w += (float)p[3];
    }
    const float dv = dinv[idx >> 6];
    const float4 b = ((const float4*)bias)[idx & 63];
    float4 r;
    r.x = fmaxf(dv * s.x + b.x, 0.f);
    r.y = fmaxf(dv * s.y + b.y, 0.f);
    r.z = fmaxf(dv * s.z + b.z, 0.f);
    r.w = fmaxf(dv * s.w + b.w, 0.f);
    ((float4*)out)[idx] = r;
}

// ---------------------------------------------------------------------------
extern "C" void kernel_launch(void* const* d_in, const int* in_sizes, int n_in,
                              void* d_out, int out_size, void* d_ws, size_t ws_size,
                              hipStream_t stream) {
    const float* input  = (const float*)d_in[0];   // [8192][512]
    const float* adj    = (const float*)d_in[1];   // [8192][8192]
    const float* weight = (const float*)d_in[2];   // [512][256]
    const float* bias   = (const float*)d_in[3];   // [256]
    float* out = (float*)d_out;                    // [8192][256]

    char* ws = (char*)d_ws;
    float*    dinv  = (float*)ws;                       // 32 KB
    char*     wt    = ws + 32768;                       // 256 KB
    char*     sT    = ws + 294912;                      // 4 MB (fp16, fragT)
    _Float16* parth = (_Float16*)(ws + 294912 + 4194304);  // (nsplit-1)*4 MB

    const size_t base = 294912 + 4194304;
    int nsplit = 1;
    if (ws_size >= base + 3ull * 4194304) nsplit = 4;      // ~17 MB
    else if (ws_size >= base + 1ull * 4194304) nsplit = 2;
    const int steps = 128 / nsplit;

    k0_wt<<<512, 256, 0, stream>>>(weight, wt);
    k12_fused<<<8448, 512, 0, stream>>>(input, adj, wt, dinv, sT);
    k3_spmm<<<dim3(256, nsplit), 512, 0, stream>>>(adj, sT, dinv, parth, out, steps);
    k4_fin<<<2048, 256, 0, stream>>>(parth, out, dinv, bias, nsplit);
}

// Round 19
// 120.199 us; speedup vs baseline: 1.2098x; 1.2098x over previous
//
#include <hip/hip_runtime.h>

// GraphConvolution: out = relu(D^-1/2 (2I - adj) D^-1/2 (input@weight) + b)
// N=8192, F_in=512, F_out=256. fp16 MFMA internally (needs 2^-12 rounding).
//
// R19 = R15 (proven 120.5us) + reverse-bx in k3: k12's rowsum streams adj
// rows 0->8191, so the HIGHEST rows are L3-resident (LRU) when k3 starts;
// k3 consumes rows top-down to match. Isolated test of the free L3 lever
// (rode confounded in R12). All else byte-identical to R15.
// R16-R18 occupancy arc verdict: 4 blk/CU loses (B pipeline depth traded
// away); BM=64 / 2 blk/CU / reg-double-buffered B is the structural optimum.

typedef _Float16 h4 __attribute__((ext_vector_type(4)));
typedef _Float16 h8 __attribute__((ext_vector_type(8)));
typedef float f4 __attribute__((ext_vector_type(4)));

__device__ __forceinline__ void gload_lds16(const void* g, void* l) {
    __builtin_amdgcn_global_load_lds(
        (const __attribute__((address_space(1))) void*)g,
        (__attribute__((address_space(3))) void*)l, 16, 0, 0);
}
__device__ __forceinline__ void gload2(const float* p, f4& x, f4& y) {
    asm volatile("global_load_dwordx4 %0, %2, off\n\t"
                 "global_load_dwordx4 %1, %2, off offset:16"
                 : "=&v"(x), "=&v"(y) : "v"(p) : "memory");
}
__device__ __forceinline__ void gloadBfrag(const char* p, h8& x, h8& y) {
    asm volatile("global_load_dwordx4 %0, %2, off\n\t"
                 "global_load_dwordx4 %1, %2, off offset:1024"
                 : "=&v"(x), "=&v"(y) : "v"(p) : "memory");
}

// ---------------------------------------------------------------------------
// k0: weight [512][256] f32 -> W^T fp16, XOR-swizzled per 128B k-chunk:
// byte ^= ((j&7)<<4)  (consumed by the fused kernel's gload_lds path).
__global__ __launch_bounds__(256) void k0_wt(const float* __restrict__ weight,
                                             char* __restrict__ wt) {
    const int idx = blockIdx.x * 256 + threadIdx.x;   // 131072 total
    const int k = idx >> 8, j = idx & 255;
    const _Float16 h = (_Float16)weight[idx];
    const int off = j * 1024 + ((k >> 6) << 7) + (((k & 63) << 1) ^ ((j & 7) << 4));
    *(_Float16*)(wt + off) = h;
}

// ---------------------------------------------------------------------------
// fragT layout of S^T (4 MB): chunk = (j>>4)*128 + (k>>6), 2048B each;
// off = chunk*2048 + ((k>>5)&1)*1024 + (((k>>3)&3)*16+(j&15))*16 + (k&7)*2.
// Lane l of a wave reading chunk base + l*16 gets exactly its MFMA B-fragment.
//
// k12: fused. bid<256: support = input@weight -> fragT (raw, no dinv).
// bid>=256: rowsum of adj row (bid-256) -> dinv. Independent ranges run
// concurrently; k2's compute hides under k1's HBM stream.
__global__ __launch_bounds__(512) void k12_fused(const float* __restrict__ input,
                                                 const float* __restrict__ adj,
                                                 const char* __restrict__ wt,
                                                 float* __restrict__ dinv,
                                                 char* __restrict__ sT) {
    __shared__ char smem[4096 + 32768];
    const int bid = (int)blockIdx.x, t = (int)threadIdx.x;

    if (bid >= 256) {   // ---- k1: rowsum, full occupancy
        const int r = bid - 256;
        const float4* rp = (const float4*)(adj + (size_t)r * 8192);
        float s = 0.f;
#pragma unroll
        for (int i = 0; i < 4; ++i) {
            float4 v = rp[t + i * 512];
            s += (v.x + v.y) + (v.z + v.w);
        }
#pragma unroll
        for (int off = 32; off > 0; off >>= 1) s += __shfl_down(s, off, 64);
        float* part = (float*)smem;
        if ((t & 63) == 0) part[t >> 6] = s;
        __syncthreads();
        if (t == 0) {
            float deg = ((part[0] + part[1]) + (part[2] + part[3])) +
                        ((part[4] + part[5]) + (part[6] + part[7]));
            dinv[r] = 1.0f / sqrtf(2.0f + deg);
        }
        return;
    }

    // ---- k2: support GEMM ----
    const int w = t >> 6, l = t & 63;
    const int r0 = bid * 32;
    const int arow = t >> 4, ak4 = t & 15;
    const int bj = l >> 3, bb = (l & 7) * 16;

    f4 acc[2][2] = {};

    for (int kt = 0; kt < 8; ++kt) {
        const int k0 = kt * 64;
        __syncthreads();
        {
            float4 v = *(const float4*)(input + (size_t)(r0 + arow) * 512 + k0 + ak4 * 4);
            h4 h;
            h[0] = (_Float16)v.x; h[1] = (_Float16)v.y;
            h[2] = (_Float16)v.z; h[3] = (_Float16)v.w;
            *(h4*)(smem + arow * 128 + ((ak4 * 8) ^ ((arow & 7) << 4))) = h;
        }
#pragma unroll
        for (int q = 0; q < 4; ++q) {
            const int c = q * 8 + w;
            gload_lds16(wt + (size_t)(c * 8 + bj) * 1024 + kt * 128 + bb,
                        smem + 4096 + c * 1024);
        }
        __syncthreads();
#pragma unroll
        for (int kk = 0; kk < 2; ++kk) {
            const int ko = kk * 64 + ((l >> 4) << 4);
            h8 a[2], b[2];
#pragma unroll
            for (int m = 0; m < 2; ++m) {
                const int r = m * 16 + (l & 15);
                a[m] = *(const h8*)(smem + r * 128 + (ko ^ ((r & 7) << 4)));
            }
#pragma unroll
            for (int n = 0; n < 2; ++n) {
                const int j = w * 32 + n * 16 + (l & 15);
                b[n] = *(const h8*)(smem + 4096 + j * 128 + (ko ^ ((j & 7) << 4)));
            }
#pragma unroll
            for (int m = 0; m < 2; ++m)
#pragma unroll
                for (int n = 0; n < 2; ++n)
                    acc[m][n] = __builtin_amdgcn_mfma_f32_16x16x32_f16(a[m], b[n], acc[m][n], 0, 0, 0);
        }
    }
#pragma unroll
    for (int m = 0; m < 2; ++m)
#pragma unroll
        for (int n = 0; n < 2; ++n) {
            const int j = w * 32 + n * 16 + (l & 15);
            const int k0r = r0 + m * 16 + ((l >> 4) << 2);
            h4 h;
#pragma unroll
            for (int r = 0; r < 4; ++r)
                h[r] = (_Float16)acc[m][n][r];
            const int off = (((j >> 4) * 128 + (k0r >> 6)) << 11) +
                            (((k0r >> 5) & 1) << 10) +
                            ((((k0r >> 3) & 3) << 4) + (j & 15)) * 16 +
                            ((k0r & 7) << 1);
            *(h4*)(sT + off) = h;
        }
}

// ---------------------------------------------------------------------------
// k3: partial[i][j] = sum_{k slice} (2I-adj)[i][k]*dinv[k] * S^T[j][k].
// BM=64, BN=256, BK=64; 8 waves x (64Mx32N); 2 blk/CU. A f32->fp16(dinv-
// scaled)->LDS dbuf; dinv slice LDS-staged (race-fixed prologue); B fragT
// ping-pong regs; counted vmcnt (6 in flight at barriers); T5 setprio.
// bx REVERSED: k3 consumes adj rows top-down to match k12's LRU residue.
__global__ __launch_bounds__(512, 4) void k3_spmm(const float* __restrict__ adj,
                                                  const char* __restrict__ sT,
                                                  const float* __restrict__ dinvg,
                                                  _Float16* __restrict__ parth,
                                                  float* __restrict__ out,
                                                  int steps) {
    __shared__ __align__(16) char smem[2][8192];   // A tiles [64 rows][128 B]
    __shared__ __align__(16) float sdinv[2048];    // dinv slice for this split
    const int t = threadIdx.x;
    const int w = t >> 6, l = t & 63;
    const int i0 = (127 - (int)blockIdx.x) * 64;   // reverse-bx (L3 locality)
    const int ks0 = (int)blockIdx.y * steps * 64;
    const int dkt = (i0 - ks0) >> 6;

    const int arow = t >> 3;
    const int ak8 = (t & 7) * 8;
    const int arow_g = i0 + arow;
    const float* aptr = adj + (size_t)arow_g * 8192 + ks0 + ak8;
    const int a_off = arow * 128 + (((t & 7) << 4) ^ ((arow & 7) << 4));

    const char* bpn0 = sT + ((size_t)(w * 2) * 128 + (ks0 >> 6)) * 2048 + l * 16;
    const char* bpn1 = bpn0 + 262144;

    f4 acc[4][2] = {};
    h8 bvA[2][2], bvB[2][2];
    f4 ax0, ay0, ax1, ay1;

    auto loadB = [&](int kt, h8 (&bv)[2][2]) {
        gloadBfrag(bpn0 + (size_t)kt * 2048, bv[0][0], bv[1][0]);
        gloadBfrag(bpn1 + (size_t)kt * 2048, bv[0][1], bv[1][1]);
    };
    auto writeA = [&](char* buf, int kt, const f4 x, const f4 y) {
        const int kb = kt * 64 + ak8;
        const float4 d0 = *(const float4*)&sdinv[kb];
        const float4 d1 = *(const float4*)&sdinv[kb + 4];
        const int kg = ks0 + kb;
        h8 h;
        if (kt == dkt) {
            h[0] = (_Float16)(d0.x * ((arow_g == kg    ) ? 2.0f - x[0] : -x[0]));
            h[1] = (_Float16)(d0.y * ((arow_g == kg + 1) ? 2.0f - x[1] : -x[1]));
            h[2] = (_Float16)(d0.z * ((arow_g == kg + 2) ? 2.0f - x[2] : -x[2]));
            h[3] = (_Float16)(d0.w * ((arow_g == kg + 3) ? 2.0f - x[3] : -x[3]));
            h[4] = (_Float16)(d1.x * ((arow_g == kg + 4) ? 2.0f - y[0] : -y[0]));
            h[5] = (_Float16)(d1.y * ((arow_g == kg + 5) ? 2.0f - y[1] : -y[1]));
            h[6] = (_Float16)(d1.z * ((arow_g == kg + 6) ? 2.0f - y[2] : -y[2]));
            h[7] = (_Float16)(d1.w * ((arow_g == kg + 7) ? 2.0f - y[3] : -y[3]));
        } else {
            h[0] = (_Float16)(-d0.x * x[0]);
            h[1] = (_Float16)(-d0.y * x[1]);
            h[2] = (_Float16)(-d0.z * x[2]);
            h[3] = (_Float16)(-d0.w * x[3]);
            h[4] = (_Float16)(-d1.x * y[0]);
            h[5] = (_Float16)(-d1.y * y[1]);
            h[6] = (_Float16)(-d1.z * y[2]);
            h[7] = (_Float16)(-d1.w * y[3]);
        }
        *(h8*)(buf + a_off) = h;
    };
    auto compute = [&](const char* A, const h8 (&bv)[2][2]) {
        __builtin_amdgcn_s_setprio(1);                       // T5
#pragma unroll
        for (int kk = 0; kk < 2; ++kk) {
            const int ko = kk * 64 + ((l >> 4) << 4);
            h8 a[4];
#pragma unroll
            for (int m = 0; m < 4; ++m) {
                const int r = m * 16 + (l & 15);
                a[m] = *(const h8*)(A + r * 128 + (ko ^ ((r & 7) << 4)));
            }
#pragma unroll
            for (int m = 0; m < 4; ++m)
#pragma unroll
                for (int n = 0; n < 2; ++n)
                    acc[m][n] = __builtin_amdgcn_mfma_f32_16x16x32_f16(a[m], bv[kk][n], acc[m][n], 0, 0, 0);
        }
        __builtin_amdgcn_s_setprio(0);                       // T5
    };

#define SBAR0() __builtin_amdgcn_sched_barrier(0)
#define WAIT_ADJ(N, X, Y)                                                     \
    asm volatile("s_waitcnt vmcnt(" #N ")" : "+v"(X), "+v"(Y) :: "memory");   \
    SBAR0();
#define WAIT_STEP(N, X, Y, BV)                                                \
    asm volatile("s_waitcnt vmcnt(" #N ")"                                    \
                 : "+v"(X), "+v"(Y), "+v"(BV[0][0]), "+v"(BV[0][1]),          \
                   "+v"(BV[1][0]), "+v"(BV[1][1]) :: "memory");               \
    SBAR0();
#define WAIT_BV(N, BV)                                                        \
    asm volatile("s_waitcnt vmcnt(" #N ")"                                    \
                 : "+v"(BV[0][0]), "+v"(BV[0][1]),                            \
                   "+v"(BV[1][0]), "+v"(BV[1][1]) :: "memory");               \
    SBAR0();
#define BARRIER()                                                             \
    asm volatile("s_waitcnt lgkmcnt(0)\n\ts_barrier" ::: "memory");           \
    SBAR0();

    // prologue (race-fixed): issue [dinvLDS, adj0 x2, B(0) x4]; vmcnt(4)
    // retires this wave's dinv+adj0; s_barrier makes ALL waves' dinv staging
    // visible before any sdinv read; writeA(0); issue adj(1); barrier ->
    // queue exits as [B(0) x4, adj(1) x2] = 6 in flight.
    gload_lds16(dinvg + ks0 + t * 4, (char*)sdinv + w * 1024);
    gload2(aptr, ax0, ay0);
    loadB(0, bvA);
    WAIT_ADJ(4, ax0, ay0)
    asm volatile("s_barrier" ::: "memory");
    SBAR0();
    writeA(smem[0], 0, ax0, ay0);
    gload2(aptr + 64, ax1, ay1);
    BARRIER()

#define BODY(kt, XC, YC, XN, YN, BVC, BVN, BUFC, BUFN)                        \
    {                                                                         \
        loadB((kt) + 1, BVN);                                                 \
        gload2(aptr + (size_t)((kt) + 2) * 64, XC, YC);                       \
        WAIT_STEP(6, XN, YN, BVC)                                             \
        writeA(BUFN, (kt) + 1, XN, YN);                                       \
        compute(BUFC, BVC);                                                   \
        BARRIER()                                                             \
    }

    for (int kt2 = 0; kt2 + 2 <= steps - 2; kt2 += 2) {
        BODY(kt2,     ax0, ay0, ax1, ay1, bvA, bvB, smem[0], smem[1])
        BODY(kt2 + 1, ax1, ay1, ax0, ay0, bvB, bvA, smem[1], smem[0])
    }
    {   // peeled kt = steps-2: load B(steps-1); no new adj
        loadB(steps - 1, bvB);
        WAIT_STEP(4, ax1, ay1, bvA)
        writeA(smem[1], steps - 1, ax1, ay1);
        compute(smem[0], bvA);
        BARRIER()
    }
    {   // peeled kt = steps-1
        WAIT_BV(0, bvB)
        compute(smem[1], bvB);
    }
#undef BODY
#undef WAIT_ADJ
#undef WAIT_STEP
#undef WAIT_BV
#undef BARRIER
#undef SBAR0

    // epilogue: last split -> f32 out; others -> fp16 partial slot.
    if (blockIdx.y == gridDim.y - 1) {
#pragma unroll
        for (int m = 0; m < 4; ++m)
#pragma unroll
            for (int n = 0; n < 2; ++n) {
                const int j = w * 32 + n * 16 + (l & 15);
                const int ib = i0 + m * 16 + ((l >> 4) << 2);
#pragma unroll
                for (int r = 0; r < 4; ++r)
                    out[(size_t)(ib + r) * 256 + j] = acc[m][n][r];
            }
    } else {
        _Float16* pslot = parth + (size_t)blockIdx.y * (8192 * 256);
#pragma unroll
        for (int m = 0; m < 4; ++m)
#pragma unroll
            for (int n = 0; n < 2; ++n) {
                const int j = w * 32 + n * 16 + (l & 15);
                const int ib = i0 + m * 16 + ((l >> 4) << 2);
#pragma unroll
                for (int r = 0; r < 4; ++r)
                    pslot[(size_t)(ib + r) * 256 + j] = (_Float16)acc[m][n][r];
            }
    }
}

// ---------------------------------------------------------------------------
// k4: out = relu(dinv[i]*(out + sum of fp16 partials) + b[j]).
__global__ __launch_bounds__(256) void k4_fin(const _Float16* __restrict__ parth,
                                              float* __restrict__ out,
                                              const float* __restrict__ dinv,
                                              const float* __restrict__ bias,
                                              int nsplit) {
    const int idx = blockIdx.x * 256 + threadIdx.x;   // 524288 float4 groups
    float4 s = ((const float4*)out)[idx];
    for (int sp = 0; sp < nsplit - 1; ++sp) {
        const h4 p = *(const h4*)(parth + (size_t)sp * (8192 * 256) + (size_t)idx * 4);
        s.x += (float)p[0]; s.y += (float)p[1];
        s.z += (float)p[2]; s.w += (float)p[3];
    }
    const float dv = dinv[idx >> 6];
    const float4 b = ((const float4*)bias)[idx & 63];
    float4 r;
    r.x = fmaxf(dv * s.x + b.x, 0.f);
    r.y = fmaxf(dv * s.y + b.y, 0.f);
    r.z = fmaxf(dv * s.z + b.z, 0.f);
    r.w = fmaxf(dv * s.w + b.w, 0.f);
    ((float4*)out)[idx] = r;
}

// ---------------------------------------------------------------------------
extern "C" void kernel_launch(void* const* d_in, const int* in_sizes, int n_in,
                              void* d_out, int out_size, void* d_ws, size_t ws_size,
                              hipStream_t stream) {
    const float* input  = (const float*)d_in[0];   // [8192][512]
    const float* adj    = (const float*)d_in[1];   // [8192][8192]
    const float* weight = (const float*)d_in[2];   // [512][256]
    const float* bias   = (const float*)d_in[3];   // [256]
    float* out = (float*)d_out;                    // [8192][256]

    char* ws = (char*)d_ws;
    float*    dinv  = (float*)ws;                       // 32 KB
    char*     wt    = ws + 32768;                       // 256 KB
    char*     sT    = ws + 294912;                      // 4 MB (fp16, fragT)
    _Float16* parth = (_Float16*)(ws + 294912 + 4194304);  // (nsplit-1)*4 MB

    const size_t base = 294912 + 4194304;
    int nsplit = 1;
    if (ws_size >= base + 3ull * 4194304) nsplit = 4;      // ~17 MB
    else if (ws_size >= base + 1ull * 4194304) nsplit = 2;
    const int steps = 128 / nsplit;

    k0_wt<<<512, 256, 0, stream>>>(weight, wt);
    k12_fused<<<8448, 512, 0, stream>>>(input, adj, wt, dinv, sT);
    k3_spmm<<<dim3(128, nsplit), 512, 0, stream>>>(adj, sT, dinv, parth, out, steps);
    k4_fin<<<2048, 256, 0, stream>>>(parth, out, dinv, bias, nsplit);
}